// Round 3
// baseline (499.362 us; speedup 1.0000x reference)
//
#include <hip/hip_runtime.h>
#include <math.h>

#define SP_IN   3136   // 56*56
#define HID     196
#define NPLANES 256
#define NB      64
#define NREM    1568   // removed per row
#define P4      784    // SP_IN/4
#define BROW    ((size_t)NB * SP_IN)   // elements per channel-chunk partial
#define POOL_BLOCKS 784
#define TR_BLOCKS   686                // 7 x 98 tiles of 32x32

// ---- K01: channel-mean pool (blocks 0..783) + W2 transpose (blocks 784..) ----
__global__ __launch_bounds__(256) void k01_pool_tr(const float* __restrict__ x,
                                                   const float* __restrict__ W2,
                                                   double* __restrict__ yp,
                                                   float* __restrict__ W2T) {
  if (blockIdx.x < POOL_BLOCKS) {
    const int gid = blockIdx.x * 256 + threadIdx.x;   // 4*64*784
    const int cc = gid / (NB * P4);
    const int r  = gid - cc * (NB * P4);
    const int b  = r / P4, p4 = r - b * P4;
    const float4* xp = (const float4*)x + (size_t)b * (NPLANES * P4)
                     + (size_t)(cc * 64) * P4 + p4;
    double a0 = 0, a1 = 0, a2 = 0, a3 = 0;
#pragma unroll 8
    for (int c = 0; c < 64; ++c) {
      float4 v = xp[(size_t)c * P4];
      a0 += v.x; a1 += v.y; a2 += v.z; a3 += v.w;
    }
    double2* op = (double2*)(yp + (size_t)cc * BROW + (size_t)b * SP_IN + p4 * 4);
    op[0] = make_double2(a0, a1);
    op[1] = make_double2(a2, a3);
  } else {
    __shared__ float tle[32][33];
    const int bx = blockIdx.x - POOL_BLOCKS;   // 0..685
    const int cx = bx % 7, cy = bx / 7;        // cx: h-tiles (196), cy: o-tiles (3136)
    const int tx = threadIdx.x & 31, ty = threadIdx.x >> 5;  // 32 x 8
    const int r0 = cy * 32, c0 = cx * 32;
    for (int i = ty; i < 32; i += 8) {
      int c = c0 + tx;
      tle[i][tx] = (c < HID) ? W2[(size_t)(r0 + i) * HID + c] : 0.f;
    }
    __syncthreads();
    for (int i = ty; i < 32; i += 8) {
      int h = c0 + i;
      if (h < HID) W2T[(size_t)h * SP_IN + (r0 + tx)] = tle[tx][i];
    }
  }
}

// ---------------- K2a: GEMM1  h = relu(W1 . y) -----------------------------
// grid (7, 64): blockIdx.x = o-chunk (28 outputs), blockIdx.y = b
__global__ __launch_bounds__(256) void k2a_gemm1(const double* __restrict__ yp,
                                                 const float* __restrict__ W1,
                                                 double* __restrict__ h) {
  __shared__ double y_s[SP_IN];  // 25 KB
  const int b = blockIdx.y, och = blockIdx.x;
  const int t = threadIdx.x, lane = t & 63, wv = t >> 6;

  for (int i = t; i < SP_IN; i += 256) {
    size_t base = (size_t)b * SP_IN + i;
    y_s[i] = (yp[base] + yp[base + BROW] + yp[base + 2 * BROW] + yp[base + 3 * BROW])
             * (1.0 / NPLANES);
  }
  __syncthreads();

  const int o0 = och * 28 + wv * 7;   // this wave's 7 outputs
  double p[7];
#pragma unroll
  for (int k = 0; k < 7; ++k) p[k] = 0.0;
  const float* wb = W1 + (size_t)o0 * SP_IN + lane;
  for (int j = 0; j < 49; ++j) {
    double yv = y_s[lane + 64 * j];
    const float* wp = wb + 64 * j;
#pragma unroll
    for (int k = 0; k < 7; ++k) p[k] += (double)wp[(size_t)k * SP_IN] * yv;
  }
#pragma unroll
  for (int k = 0; k < 7; ++k) {
    double v = p[k];
#pragma unroll
    for (int d = 32; d; d >>= 1) v += __shfl_xor(v, d, 64);
    if (lane == 0) h[(size_t)b * HID + o0 + k] = v > 0.0 ? v : 0.0;
  }
}

__device__ __forceinline__ unsigned int fkey(float f) {
  unsigned int u = __float_as_uint(f);
  return (u & 0x80000000u) ? ~u : (u | 0x80000000u);  // monotone total order
}

// ---- K2bc: GEMM2 (into LDS) + exact top-k mask + sigmoid, one block per b ----
__global__ __launch_bounds__(256, 1) void k2bc(const double* __restrict__ h,
                                               const float* __restrict__ W2T,
                                               float* __restrict__ y2m) {
  __shared__ double pre_s[SP_IN];       // 25 KB
  __shared__ double h_s[HID];
  __shared__ unsigned int hist4[4][256];  // per-wave histograms, 4 KB
  __shared__ unsigned int hist[256];
  __shared__ unsigned char rm_s[SP_IN];
  __shared__ int eqidx[64];
  __shared__ int eqcnt;
  __shared__ unsigned int prefix_s;
  __shared__ int rank_s;

  const int b = blockIdx.x;
  const int t = threadIdx.x;
  const int lane = t & 63, wv = t >> 6;

  for (int i = t; i < HID; i += 256) h_s[i] = h[(size_t)b * HID + i];
  if (t == 0) { eqcnt = 0; prefix_s = 0; rank_s = NREM; }
  __syncthreads();

  // GEMM2: pre[o] = sum_h W2T[h][o] * h_s[h]  (same per-output summation order
  // as round-2 k2b: hh = 0..195 sequential -> bit-identical results)
  for (int o = t; o < SP_IN; o += 256) {
    double a = 0.0;
    const float* wp = W2T + o;
#pragma unroll 14
    for (int hh = 0; hh < HID; ++hh) a += (double)wp[(size_t)hh * SP_IN] * h_s[hh];
    pre_s[o] = a;
  }
  __syncthreads();

  // Radix select (MSB-first, 4x8-bit) for the NREM-th smallest float key.
  for (int shift = 24; shift >= 0; shift -= 8) {
    hist4[0][t] = 0; hist4[1][t] = 0; hist4[2][t] = 0; hist4[3][t] = 0;
    __syncthreads();
    const unsigned int pfx = prefix_s;
    const unsigned int pmask = (shift == 24) ? 0u : (0xFFFFFFFFu << (shift + 8));
    const int r = rank_s;
    for (int i = t; i < SP_IN; i += 256) {
      unsigned int k = fkey((float)pre_s[i]);
      if ((k & pmask) == pfx) atomicAdd(&hist4[wv][(k >> shift) & 0xFFu], 1u);
    }
    __syncthreads();
    hist[t] = hist4[0][t] + hist4[1][t] + hist4[2][t] + hist4[3][t];
    __syncthreads();
    if (wv == 0) {  // wave-parallel scan of the 256 bins
      unsigned int h0 = hist[lane * 4], h1 = hist[lane * 4 + 1],
                   h2 = hist[lane * 4 + 2], h3 = hist[lane * 4 + 3];
      unsigned int s = h0 + h1 + h2 + h3;
      unsigned int c = s;
#pragma unroll
      for (int d = 1; d < 64; d <<= 1) {
        unsigned int vv = __shfl_up(c, d, 64);
        if (lane >= d) c += vv;
      }
      unsigned int excl = c - s;
      if (excl < (unsigned)r && c >= (unsigned)r) {  // exactly one lane
        unsigned int cum = excl;
        int bsel = lane * 4;
        if (cum + h0 < (unsigned)r) { cum += h0; ++bsel;
          if (cum + h1 < (unsigned)r) { cum += h1; ++bsel;
            if (cum + h2 < (unsigned)r) { cum += h2; ++bsel; } } }
        rank_s = r - (int)cum;
        prefix_s = pfx | ((unsigned)bsel << shift);
      }
    }
    __syncthreads();
  }
  const unsigned int ustar = prefix_s;  // key of the boundary element
  const int need_eq = rank_s;           // how many key==ustar elems to remove

  for (int i = t; i < SP_IN; i += 256) {
    unsigned int k = fkey((float)pre_s[i]);
    rm_s[i] = (k < ustar) ? 1 : 0;
    if (k == ustar) { int p = atomicAdd(&eqcnt, 1); if (p < 64) eqidx[p] = i; }
  }
  __syncthreads();
  if (t == 0) {  // remove need_eq smallest by (fp64 value, index) — stable-argsort semantics
    int m = eqcnt < 64 ? eqcnt : 64;
    int ne = need_eq < m ? need_eq : m;
    unsigned long long used = 0ull;
    for (int cnt = 0; cnt < ne; ++cnt) {
      int best = -1;
      for (int j = 0; j < m; ++j) {
        if (used & (1ull << j)) continue;
        if (best < 0) { best = j; continue; }
        int ib = eqidx[best], ij = eqidx[j];
        double vb = pre_s[ib], vj = pre_s[ij];
        if (vj < vb || (vj == vb && ij < ib)) best = j;
      }
      used |= (1ull << best);
      rm_s[eqidx[best]] = 1;
    }
  }
  __syncthreads();

  for (int i = t; i < SP_IN; i += 256) {
    double sg = 1.0 / (1.0 + exp(-pre_s[i]));
    y2m[(size_t)b * SP_IN + i] = rm_s[i] ? 0.f : (float)sg;
  }
}

// ---------------- K3: broadcast masked row over 256 planes -----------------
__global__ __launch_bounds__(256) void k3_bcast(const float* __restrict__ y2m,
                                                float* __restrict__ out) {
  const int idx = blockIdx.x * 256 + threadIdx.x;  // 64 b * 64 cgroups * 784 p4
  const int p4 = idx % P4;
  const int rest = idx / P4;
  const int cg = rest & 63;
  const int b = rest >> 6;
  float4 v = ((const float4*)y2m)[b * P4 + p4];
  float4* op = (float4*)out + (size_t)b * (NPLANES * P4) + (size_t)(cg * 4) * P4 + p4;
  op[0] = v;
  op[P4] = v;
  op[2 * P4] = v;
  op[3 * P4] = v;
}

extern "C" void kernel_launch(void* const* d_in, const int* in_sizes, int n_in,
                              void* d_out, int out_size, void* d_ws, size_t ws_size,
                              hipStream_t stream) {
  (void)in_sizes; (void)n_in; (void)out_size; (void)ws_size;
  const float* x  = (const float*)d_in[0];
  const float* W1 = (const float*)d_in[1];
  const float* W2 = (const float*)d_in[2];
  float* out = (float*)d_out;

  // ws layout (bytes):
  //   [0, 2458624)            W2T   (196*3136*4)      live k01..k2bc
  //   [2458624, 8881152)      yp    (4*64*3136*8)     live k01..k2a
  //   [8881152, 8981504)      h     (64*196*8)        live k2a..k2bc
  //   y2m at 4064256 aliases yp (dead after k2a)      live k2bc..k3
  char* ws = (char*)d_ws;
  float*  W2T = (float*)ws;
  double* yp  = (double*)(ws + 2458624);
  double* h   = (double*)(ws + 8881152);
  float*  y2m = (float*)(ws + 4064256);

  k01_pool_tr<<<dim3(POOL_BLOCKS + TR_BLOCKS), dim3(256), 0, stream>>>(x, W2, yp, W2T);
  k2a_gemm1<<<dim3(7, NB), dim3(256), 0, stream>>>(yp, W1, h);
  k2bc<<<dim3(NB), dim3(256), 0, stream>>>(h, W2T, y2m);
  k3_bcast<<<dim3(12544), dim3(256), 0, stream>>>(y2m, out);
}

// Round 5
// 387.751 us; speedup vs baseline: 1.2878x; 1.2878x over previous
//
#include <hip/hip_runtime.h>
#include <math.h>

#define SP_IN   3136   // 56*56
#define HID     196
#define NPLANES 256
#define NB      64
#define NREM    1568   // removed per row
#define P4      784    // SP_IN/4
#define BROW    ((size_t)NB * SP_IN)   // elements per channel-chunk partial
#define POOL_BLOCKS 784
#define TR_BLOCKS   686                // 7 x 98 tiles of 32x32

typedef float nt_f4 __attribute__((ext_vector_type(4)));  // nontemporal-builtin-compatible

// ---- K01: channel-mean pool (blocks 0..783) + W2 transpose (blocks 784..) ----
__global__ __launch_bounds__(256) void k01_pool_tr(const float* __restrict__ x,
                                                   const float* __restrict__ W2,
                                                   double* __restrict__ yp,
                                                   float* __restrict__ W2T) {
  if (blockIdx.x < POOL_BLOCKS) {
    const int gid = blockIdx.x * 256 + threadIdx.x;   // 4*64*784
    const int cc = gid / (NB * P4);
    const int r  = gid - cc * (NB * P4);
    const int b  = r / P4, p4 = r - b * P4;
    const nt_f4* xp = (const nt_f4*)x + (size_t)b * (NPLANES * P4)
                    + (size_t)(cc * 64) * P4 + p4;
    double a0 = 0, a1 = 0, a2 = 0, a3 = 0;
#pragma unroll 8
    for (int c = 0; c < 64; ++c) {
      nt_f4 v = __builtin_nontemporal_load(xp + (size_t)c * P4);  // x is read exactly once
      a0 += v.x; a1 += v.y; a2 += v.z; a3 += v.w;
    }
    double2* op = (double2*)(yp + (size_t)cc * BROW + (size_t)b * SP_IN + p4 * 4);
    op[0] = make_double2(a0, a1);
    op[1] = make_double2(a2, a3);
  } else {
    __shared__ float tle[32][33];
    const int bx = blockIdx.x - POOL_BLOCKS;   // 0..685
    const int cx = bx % 7, cy = bx / 7;        // cx: h-tiles (196), cy: o-tiles (3136)
    const int tx = threadIdx.x & 31, ty = threadIdx.x >> 5;  // 32 x 8
    const int r0 = cy * 32, c0 = cx * 32;
    for (int i = ty; i < 32; i += 8) {
      int c = c0 + tx;
      tle[i][tx] = (c < HID) ? W2[(size_t)(r0 + i) * HID + c] : 0.f;
    }
    __syncthreads();
    for (int i = ty; i < 32; i += 8) {
      int h = c0 + i;
      if (h < HID) W2T[(size_t)h * SP_IN + (r0 + tx)] = tle[tx][i];
    }
  }
}

// ---------------- K2a: GEMM1  h = relu(W1 . y) -----------------------------
// grid (7, 64): blockIdx.x = o-chunk (28 outputs), blockIdx.y = b
__global__ __launch_bounds__(256) void k2a_gemm1(const double* __restrict__ yp,
                                                 const float* __restrict__ W1,
                                                 double* __restrict__ h) {
  __shared__ double y_s[SP_IN];  // 25 KB
  const int b = blockIdx.y, och = blockIdx.x;
  const int t = threadIdx.x, lane = t & 63, wv = t >> 6;

  for (int i = t; i < SP_IN; i += 256) {
    size_t base = (size_t)b * SP_IN + i;
    y_s[i] = (yp[base] + yp[base + BROW] + yp[base + 2 * BROW] + yp[base + 3 * BROW])
             * (1.0 / NPLANES);
  }
  __syncthreads();

  const int o0 = och * 28 + wv * 7;   // this wave's 7 outputs
  double p[7];
#pragma unroll
  for (int k = 0; k < 7; ++k) p[k] = 0.0;
  const float* wb = W1 + (size_t)o0 * SP_IN + lane;
  for (int j = 0; j < 49; ++j) {
    double yv = y_s[lane + 64 * j];
    const float* wp = wb + 64 * j;
#pragma unroll
    for (int k = 0; k < 7; ++k) p[k] += (double)wp[(size_t)k * SP_IN] * yv;
  }
#pragma unroll
  for (int k = 0; k < 7; ++k) {
    double v = p[k];
#pragma unroll
    for (int d = 32; d; d >>= 1) v += __shfl_xor(v, d, 64);
    if (lane == 0) h[(size_t)b * HID + o0 + k] = v > 0.0 ? v : 0.0;
  }
}

// ---------------- K2b: GEMM2  pre = W2T^T . h (thread per output) ----------
// grid (13, 64): o = blockIdx.x*256 + t, b = blockIdx.y   (832 blocks — keep
// full-device parallelism; the round-3 64-block fusion of this GEMM was the
// +86 us regression)
__global__ __launch_bounds__(256) void k2b_gemm2(const double* __restrict__ h,
                                                 const float* __restrict__ W2T,
                                                 double* __restrict__ pre) {
  __shared__ double h_s[HID];
  const int b = blockIdx.y;
  const int o = blockIdx.x * 256 + threadIdx.x;
  for (int i = threadIdx.x; i < HID; i += 256) h_s[i] = h[(size_t)b * HID + i];
  __syncthreads();
  if (o < SP_IN) {
    double a = 0.0;
    const float* wp = W2T + o;
#pragma unroll 14
    for (int hh = 0; hh < HID; ++hh) a += (double)wp[(size_t)hh * SP_IN] * h_s[hh];
    pre[(size_t)b * SP_IN + o] = a;
  }
}

__device__ __forceinline__ unsigned int fkey(float f) {
  unsigned int u = __float_as_uint(f);
  return (u & 0x80000000u) ? ~u : (u | 0x80000000u);  // monotone total order
}

// ---------------- K2c: per-row exact top-k mask + sigmoid ------------------
__global__ __launch_bounds__(256, 1) void k2c_select(const double* __restrict__ pre,
                                                     float* __restrict__ y2m) {
  __shared__ double pre_s[SP_IN];       // 25 KB
  __shared__ unsigned int hist4[4][256];  // per-wave histograms
  __shared__ unsigned int hist[256];
  __shared__ unsigned char rm_s[SP_IN];
  __shared__ int eqidx[64];
  __shared__ int eqcnt;
  __shared__ unsigned int prefix_s;
  __shared__ int rank_s;

  const int b = blockIdx.x;
  const int t = threadIdx.x;
  const int lane = t & 63, wv = t >> 6;

  for (int i = t; i < SP_IN; i += 256) pre_s[i] = pre[(size_t)b * SP_IN + i];
  if (t == 0) { eqcnt = 0; prefix_s = 0; rank_s = NREM; }
  __syncthreads();

  // Radix select (MSB-first, 4x8-bit) for the NREM-th smallest float key.
  for (int shift = 24; shift >= 0; shift -= 8) {
    hist4[0][t] = 0; hist4[1][t] = 0; hist4[2][t] = 0; hist4[3][t] = 0;
    __syncthreads();
    const unsigned int pfx = prefix_s;
    const unsigned int pmask = (shift == 24) ? 0u : (0xFFFFFFFFu << (shift + 8));
    const int r = rank_s;
    for (int i = t; i < SP_IN; i += 256) {
      unsigned int k = fkey((float)pre_s[i]);
      if ((k & pmask) == pfx) atomicAdd(&hist4[wv][(k >> shift) & 0xFFu], 1u);
    }
    __syncthreads();
    hist[t] = hist4[0][t] + hist4[1][t] + hist4[2][t] + hist4[3][t];
    __syncthreads();
    if (wv == 0) {  // wave-parallel scan of the 256 bins
      unsigned int h0 = hist[lane * 4], h1 = hist[lane * 4 + 1],
                   h2 = hist[lane * 4 + 2], h3 = hist[lane * 4 + 3];
      unsigned int s = h0 + h1 + h2 + h3;
      unsigned int c = s;
#pragma unroll
      for (int d = 1; d < 64; d <<= 1) {
        unsigned int vv = __shfl_up(c, d, 64);
        if (lane >= d) c += vv;
      }
      unsigned int excl = c - s;
      if (excl < (unsigned)r && c >= (unsigned)r) {  // exactly one lane
        unsigned int cum = excl;
        int bsel = lane * 4;
        if (cum + h0 < (unsigned)r) { cum += h0; ++bsel;
          if (cum + h1 < (unsigned)r) { cum += h1; ++bsel;
            if (cum + h2 < (unsigned)r) { cum += h2; ++bsel; } } }
        rank_s = r - (int)cum;
        prefix_s = pfx | ((unsigned)bsel << shift);
      }
    }
    __syncthreads();
  }
  const unsigned int ustar = prefix_s;  // key of the boundary element
  const int need_eq = rank_s;           // how many key==ustar elems to remove

  for (int i = t; i < SP_IN; i += 256) {
    unsigned int k = fkey((float)pre_s[i]);
    rm_s[i] = (k < ustar) ? 1 : 0;
    if (k == ustar) { int p = atomicAdd(&eqcnt, 1); if (p < 64) eqidx[p] = i; }
  }
  __syncthreads();
  if (t == 0) {  // remove need_eq smallest by (fp64 value, index) — stable-argsort semantics
    int m = eqcnt < 64 ? eqcnt : 64;
    int ne = need_eq < m ? need_eq : m;
    unsigned long long used = 0ull;
    for (int cnt = 0; cnt < ne; ++cnt) {
      int best = -1;
      for (int j = 0; j < m; ++j) {
        if (used & (1ull << j)) continue;
        if (best < 0) { best = j; continue; }
        int ib = eqidx[best], ij = eqidx[j];
        double vb = pre_s[ib], vj = pre_s[ij];
        if (vj < vb || (vj == vb && ij < ib)) best = j;
      }
      used |= (1ull << best);
      rm_s[eqidx[best]] = 1;
    }
  }
  __syncthreads();

  for (int i = t; i < SP_IN; i += 256) {
    double sg = 1.0 / (1.0 + exp(-pre_s[i]));
    y2m[(size_t)b * SP_IN + i] = rm_s[i] ? 0.f : (float)sg;
  }
}

// ---------------- K3: broadcast masked row over 256 planes -----------------
__global__ __launch_bounds__(256) void k3_bcast(const float* __restrict__ y2m,
                                                float* __restrict__ out) {
  const int idx = blockIdx.x * 256 + threadIdx.x;  // 64 b * 64 cgroups * 784 p4
  const int p4 = idx % P4;
  const int rest = idx / P4;
  const int cg = rest & 63;
  const int b = rest >> 6;
  nt_f4 v = ((const nt_f4*)y2m)[b * P4 + p4];
  nt_f4* op = (nt_f4*)out + (size_t)b * (NPLANES * P4) + (size_t)(cg * 4) * P4 + p4;
  __builtin_nontemporal_store(v, op);            // out is write-once, never re-read
  __builtin_nontemporal_store(v, op + P4);
  __builtin_nontemporal_store(v, op + 2 * P4);
  __builtin_nontemporal_store(v, op + 3 * P4);
}

extern "C" void kernel_launch(void* const* d_in, const int* in_sizes, int n_in,
                              void* d_out, int out_size, void* d_ws, size_t ws_size,
                              hipStream_t stream) {
  (void)in_sizes; (void)n_in; (void)out_size; (void)ws_size;
  const float* x  = (const float*)d_in[0];
  const float* W1 = (const float*)d_in[1];
  const float* W2 = (const float*)d_in[2];
  float* out = (float*)d_out;

  // ws layout (bytes) — fully disjoint, no aliasing:
  //   [0,        2458624)   W2T  196*3136*4
  //   [2458624,  8881152)   yp   4*64*3136*8
  //   [8881152,  8981504)   h    64*196*8
  //   [8981504, 10587136)   pre  64*3136*8
  //   [10587136,11389952)   y2m  64*3136*4
  char* ws = (char*)d_ws;
  float*  W2T = (float*)ws;
  double* yp  = (double*)(ws + 2458624);
  double* h   = (double*)(ws + 8881152);
  double* pre = (double*)(ws + 8981504);
  float*  y2m = (float*)(ws + 10587136);

  k01_pool_tr<<<dim3(POOL_BLOCKS + TR_BLOCKS), dim3(256), 0, stream>>>(x, W2, yp, W2T);
  k2a_gemm1<<<dim3(7, NB), dim3(256), 0, stream>>>(yp, W1, h);
  k2b_gemm2<<<dim3(13, NB), dim3(256), 0, stream>>>(h, W2T, pre);
  k2c_select<<<dim3(NB), dim3(256), 0, stream>>>(pre, y2m);
  k3_bcast<<<dim3(12544), dim3(256), 0, stream>>>(y2m, out);
}

// Round 6
// 381.500 us; speedup vs baseline: 1.3089x; 1.0164x over previous
//
#include <hip/hip_runtime.h>
#include <math.h>

#define SP_IN   3136   // 56*56
#define HID     196
#define NPLANES 256
#define NB      64
#define NREM    1568   // removed per row
#define P4      784    // SP_IN/4
#define BROW    ((size_t)NB * SP_IN)   // elements per channel-chunk partial
#define POOL_BLOCKS 784
#define TR_BLOCKS   686                // 7 x 98 tiles of 32x32

typedef float nt_f4 __attribute__((ext_vector_type(4)));  // nontemporal-builtin-compatible

// ---- K01: W2 transpose (blocks 0..685, short — dispatched first so they fill
// ---- the occupancy ramp) + channel-mean pool (blocks 686..1469) -------------
__global__ __launch_bounds__(256) void k01_pool_tr(const float* __restrict__ x,
                                                   const float* __restrict__ W2,
                                                   double* __restrict__ yp,
                                                   float* __restrict__ W2T) {
  if (blockIdx.x >= TR_BLOCKS) {
    const int gid = (blockIdx.x - TR_BLOCKS) * 256 + threadIdx.x;   // 4*64*784
    const int cc = gid / (NB * P4);
    const int r  = gid - cc * (NB * P4);
    const int b  = r / P4, p4 = r - b * P4;
    const nt_f4* xp = (const nt_f4*)x + (size_t)b * (NPLANES * P4)
                    + (size_t)(cc * 64) * P4 + p4;
    double a0 = 0, a1 = 0, a2 = 0, a3 = 0;
#pragma unroll 8
    for (int c = 0; c < 64; ++c) {
      nt_f4 v = __builtin_nontemporal_load(xp + (size_t)c * P4);  // x is read exactly once
      a0 += v.x; a1 += v.y; a2 += v.z; a3 += v.w;
    }
    double2* op = (double2*)(yp + (size_t)cc * BROW + (size_t)b * SP_IN + p4 * 4);
    op[0] = make_double2(a0, a1);
    op[1] = make_double2(a2, a3);
  } else {
    __shared__ float tle[32][33];
    const int bx = blockIdx.x;                 // 0..685
    const int cx = bx % 7, cy = bx / 7;        // cx: h-tiles (196), cy: o-tiles (3136)
    const int tx = threadIdx.x & 31, ty = threadIdx.x >> 5;  // 32 x 8
    const int r0 = cy * 32, c0 = cx * 32;
    for (int i = ty; i < 32; i += 8) {
      int c = c0 + tx;
      tle[i][tx] = (c < HID) ? W2[(size_t)(r0 + i) * HID + c] : 0.f;
    }
    __syncthreads();
    for (int i = ty; i < 32; i += 8) {
      int h = c0 + i;
      if (h < HID) W2T[(size_t)h * SP_IN + (r0 + tx)] = tle[tx][i];
    }
  }
}

// ---------------- K2a: GEMM1  h = relu(W1 . y) -----------------------------
// grid (7, 64): blockIdx.x = o-chunk (28 outputs), blockIdx.y = b
__global__ __launch_bounds__(256) void k2a_gemm1(const double* __restrict__ yp,
                                                 const float* __restrict__ W1,
                                                 double* __restrict__ h) {
  __shared__ double y_s[SP_IN];  // 25 KB
  const int b = blockIdx.y, och = blockIdx.x;
  const int t = threadIdx.x, lane = t & 63, wv = t >> 6;

  for (int i = t; i < SP_IN; i += 256) {
    size_t base = (size_t)b * SP_IN + i;
    y_s[i] = (yp[base] + yp[base + BROW] + yp[base + 2 * BROW] + yp[base + 3 * BROW])
             * (1.0 / NPLANES);
  }
  __syncthreads();

  const int o0 = och * 28 + wv * 7;   // this wave's 7 outputs
  double p[7];
#pragma unroll
  for (int k = 0; k < 7; ++k) p[k] = 0.0;
  const float* wb = W1 + (size_t)o0 * SP_IN + lane;
  for (int j = 0; j < 49; ++j) {
    double yv = y_s[lane + 64 * j];
    const float* wp = wb + 64 * j;
#pragma unroll
    for (int k = 0; k < 7; ++k) p[k] += (double)wp[(size_t)k * SP_IN] * yv;
  }
#pragma unroll
  for (int k = 0; k < 7; ++k) {
    double v = p[k];
#pragma unroll
    for (int d = 32; d; d >>= 1) v += __shfl_xor(v, d, 64);
    if (lane == 0) h[(size_t)b * HID + o0 + k] = v > 0.0 ? v : 0.0;
  }
}

// ---------------- K2b: GEMM2  pre = W2T^T . h (thread per output) ----------
// grid (13, 64) = 832 blocks — full-device parallelism; fusing this into a
// 64-block kernel was the round-3 +86 us regression. Keep it separate.
__global__ __launch_bounds__(256) void k2b_gemm2(const double* __restrict__ h,
                                                 const float* __restrict__ W2T,
                                                 double* __restrict__ pre) {
  __shared__ double h_s[HID];
  const int b = blockIdx.y;
  const int o = blockIdx.x * 256 + threadIdx.x;
  for (int i = threadIdx.x; i < HID; i += 256) h_s[i] = h[(size_t)b * HID + i];
  __syncthreads();
  if (o < SP_IN) {
    double a = 0.0;
    const float* wp = W2T + o;
#pragma unroll 14
    for (int hh = 0; hh < HID; ++hh) a += (double)wp[(size_t)hh * SP_IN] * h_s[hh];
    pre[(size_t)b * SP_IN + o] = a;
  }
}

__device__ __forceinline__ unsigned int fkey(float f) {
  unsigned int u = __float_as_uint(f);
  return (u & 0x80000000u) ? ~u : (u | 0x80000000u);  // monotone total order
}

// ---------------- K2c: per-row exact top-k mask + sigmoid ------------------
// 1024 threads (16 waves): the kernel is latency-bound on 64 CUs; 16 waves/CU
// quarters the strided-pass length vs 256 threads. Histogram sums are
// order-independent -> bit-identical result.
__global__ __launch_bounds__(1024, 1) void k2c_select(const double* __restrict__ pre,
                                                      float* __restrict__ y2m) {
  __shared__ double pre_s[SP_IN];          // 25 KB
  __shared__ unsigned int hist16[16][256]; // per-wave histograms, 16 KB
  __shared__ unsigned int hist[256];
  __shared__ unsigned char rm_s[SP_IN];
  __shared__ int eqidx[64];
  __shared__ int eqcnt;
  __shared__ unsigned int prefix_s;
  __shared__ int rank_s;

  const int b = blockIdx.x;
  const int t = threadIdx.x;               // 0..1023
  const int lane = t & 63, wv = t >> 6;    // wv 0..15

  for (int i = t; i < SP_IN; i += 1024) pre_s[i] = pre[(size_t)b * SP_IN + i];
  if (t == 0) { eqcnt = 0; prefix_s = 0; rank_s = NREM; }
  __syncthreads();

  // Radix select (MSB-first, 4x8-bit) for the NREM-th smallest float key.
  for (int shift = 24; shift >= 0; shift -= 8) {
#pragma unroll
    for (int i = t; i < 16 * 256; i += 1024) ((unsigned int*)hist16)[i] = 0;
    __syncthreads();
    const unsigned int pfx = prefix_s;
    const unsigned int pmask = (shift == 24) ? 0u : (0xFFFFFFFFu << (shift + 8));
    const int r = rank_s;
    for (int i = t; i < SP_IN; i += 1024) {
      unsigned int k = fkey((float)pre_s[i]);
      if ((k & pmask) == pfx) atomicAdd(&hist16[wv][(k >> shift) & 0xFFu], 1u);
    }
    __syncthreads();
    if (t < 256) {
      unsigned int s = 0;
#pragma unroll
      for (int w = 0; w < 16; ++w) s += hist16[w][t];
      hist[t] = s;
    }
    __syncthreads();
    if (wv == 0) {  // wave-parallel scan of the 256 bins
      unsigned int h0 = hist[lane * 4], h1 = hist[lane * 4 + 1],
                   h2 = hist[lane * 4 + 2], h3 = hist[lane * 4 + 3];
      unsigned int s = h0 + h1 + h2 + h3;
      unsigned int c = s;
#pragma unroll
      for (int d = 1; d < 64; d <<= 1) {
        unsigned int vv = __shfl_up(c, d, 64);
        if (lane >= d) c += vv;
      }
      unsigned int excl = c - s;
      if (excl < (unsigned)r && c >= (unsigned)r) {  // exactly one lane
        unsigned int cum = excl;
        int bsel = lane * 4;
        if (cum + h0 < (unsigned)r) { cum += h0; ++bsel;
          if (cum + h1 < (unsigned)r) { cum += h1; ++bsel;
            if (cum + h2 < (unsigned)r) { cum += h2; ++bsel; } } }
        rank_s = r - (int)cum;
        prefix_s = pfx | ((unsigned)bsel << shift);
      }
    }
    __syncthreads();
  }
  const unsigned int ustar = prefix_s;  // key of the boundary element
  const int need_eq = rank_s;           // how many key==ustar elems to remove

  for (int i = t; i < SP_IN; i += 1024) {
    unsigned int k = fkey((float)pre_s[i]);
    rm_s[i] = (k < ustar) ? 1 : 0;
    if (k == ustar) { int p = atomicAdd(&eqcnt, 1); if (p < 64) eqidx[p] = i; }
  }
  __syncthreads();
  if (t == 0) {  // remove need_eq smallest by (fp64 value, index) — stable-argsort semantics
    int m = eqcnt < 64 ? eqcnt : 64;
    int ne = need_eq < m ? need_eq : m;
    unsigned long long used = 0ull;
    for (int cnt = 0; cnt < ne; ++cnt) {
      int best = -1;
      for (int j = 0; j < m; ++j) {
        if (used & (1ull << j)) continue;
        if (best < 0) { best = j; continue; }
        int ib = eqidx[best], ij = eqidx[j];
        double vb = pre_s[ib], vj = pre_s[ij];
        if (vj < vb || (vj == vb && ij < ib)) best = j;
      }
      used |= (1ull << best);
      rm_s[eqidx[best]] = 1;
    }
  }
  __syncthreads();

  for (int i = t; i < SP_IN; i += 1024) {
    double sg = 1.0 / (1.0 + exp(-pre_s[i]));
    y2m[(size_t)b * SP_IN + i] = rm_s[i] ? 0.f : (float)sg;
  }
}

// ---------------- K3: broadcast masked row over 256 planes -----------------
__global__ __launch_bounds__(256) void k3_bcast(const float* __restrict__ y2m,
                                                float* __restrict__ out) {
  const int idx = blockIdx.x * 256 + threadIdx.x;  // 64 b * 64 cgroups * 784 p4
  const int p4 = idx % P4;
  const int rest = idx / P4;
  const int cg = rest & 63;
  const int b = rest >> 6;
  nt_f4 v = ((const nt_f4*)y2m)[b * P4 + p4];
  nt_f4* op = (nt_f4*)out + (size_t)b * (NPLANES * P4) + (size_t)(cg * 4) * P4 + p4;
  __builtin_nontemporal_store(v, op);            // out is write-once, never re-read
  __builtin_nontemporal_store(v, op + P4);
  __builtin_nontemporal_store(v, op + 2 * P4);
  __builtin_nontemporal_store(v, op + 3 * P4);
}

extern "C" void kernel_launch(void* const* d_in, const int* in_sizes, int n_in,
                              void* d_out, int out_size, void* d_ws, size_t ws_size,
                              hipStream_t stream) {
  (void)in_sizes; (void)n_in; (void)out_size; (void)ws_size;
  const float* x  = (const float*)d_in[0];
  const float* W1 = (const float*)d_in[1];
  const float* W2 = (const float*)d_in[2];
  float* out = (float*)d_out;

  // ws layout (bytes) — fully disjoint, no aliasing:
  //   [0,        2458624)   W2T  196*3136*4
  //   [2458624,  8881152)   yp   4*64*3136*8
  //   [8881152,  8981504)   h    64*196*8
  //   [8981504, 10587136)   pre  64*3136*8
  //   [10587136,11389952)   y2m  64*3136*4
  char* ws = (char*)d_ws;
  float*  W2T = (float*)ws;
  double* yp  = (double*)(ws + 2458624);
  double* h   = (double*)(ws + 8881152);
  double* pre = (double*)(ws + 8981504);
  float*  y2m = (float*)(ws + 10587136);

  k01_pool_tr<<<dim3(TR_BLOCKS + POOL_BLOCKS), dim3(256), 0, stream>>>(x, W2, yp, W2T);
  k2a_gemm1<<<dim3(7, NB), dim3(256), 0, stream>>>(yp, W1, h);
  k2b_gemm2<<<dim3(13, NB), dim3(256), 0, stream>>>(h, W2T, pre);
  k2c_select<<<dim3(NB), dim3(1024), 0, stream>>>(pre, y2m);
  k3_bcast<<<dim3(12544), dim3(256), 0, stream>>>(y2m, out);
}